// Round 2
// baseline (460.029 us; speedup 1.0000x reference)
//
#include <hip/hip_runtime.h>

#define B_DIM   256
#define T_STEPS 2000
#define F_DIM   128
#define N_ROWS  (B_DIM * T_STEPS)         // 512000
#define N_GRP   (N_ROWS / 4)              // 128000 groups of 4 rows

// ---------------------------------------------------------------------------
// Kernel A: cur[t][b] = dot(x[b,t,:], W) + bias   (pure HBM stream, 262 MB)
// 16 lanes per row; summation order bit-identical to the verified R1 kernel:
//   per-lane 4-elem fma chain, (lo)+(hi) replaces the m=16 xor step,
//   then xor-tree m=8,4,2,1.
// ---------------------------------------------------------------------------
__global__ __launch_bounds__(256) void dense_rows(
    const float* __restrict__ x, const float* __restrict__ W,
    const float* __restrict__ bias, float* __restrict__ curT) {
  const int tid    = threadIdx.x;
  const int lane   = tid & 63;
  const int sub    = lane & 15;   // float4 index within row (low half)
  const int grp    = lane >> 4;   // row within the wave's 4-row group
  const int waveId = (blockIdx.x * 256 + tid) >> 6;
  const int nWaves = gridDim.x * 4;

  const float4 wlo = ((const float4*)W)[sub];
  const float4 whi = ((const float4*)W)[sub + 16];
  const float  bs  = bias[0];

  for (int g = waveId; g < N_GRP; g += nWaves) {
    const int rid0 = g * 4;                 // 4 rows, same batch (2000 % 4 == 0)
    const int b    = rid0 / T_STEPS;        // magic-div by constant
    const int t0   = rid0 - b * T_STEPS;
    const int rid  = rid0 + grp;

    const float4* row = (const float4*)(x + (size_t)rid * F_DIM);
    const float4  xl  = row[sub];
    const float4  xh  = row[sub + 16];

    float pl = xl.x * wlo.x;
    pl = fmaf(xl.y, wlo.y, pl);
    pl = fmaf(xl.z, wlo.z, pl);
    pl = fmaf(xl.w, wlo.w, pl);
    float ph = xh.x * whi.x;
    ph = fmaf(xh.y, whi.y, ph);
    ph = fmaf(xh.z, whi.z, ph);
    ph = fmaf(xh.w, whi.w, ph);

    float s = pl + ph;                       // == p + shfl_xor(p,16) at lanes sub<16
    s += __shfl_xor(s, 8, 64);
    s += __shfl_xor(s, 4, 64);
    s += __shfl_xor(s, 2, 64);
    s += __shfl_xor(s, 1, 64);

    if (sub == 0) curT[(t0 + grp) * B_DIM + b] = s + bs;
  }
}

// ---------------------------------------------------------------------------
// Kernel B: LIF scan. One lane per batch element; 4 blocks x 64 threads.
// Tile-64 register double-buffer for cur loads; spikes staged in LDS
// (pitch 65 -> conflict-free) and flushed as coalesced 256B rows.
// ---------------------------------------------------------------------------
__global__ __launch_bounds__(64) void lif_scan(
    const float* __restrict__ curT, float* __restrict__ out) {
  const float BETA = 0.8807970779778823f;  // sigmoid(2.0)
  const float VTH  = 1.0f;

  __shared__ float sb[64 * 65];
  const int lane = threadIdx.x;            // 0..63
  const int boff = blockIdx.x * 64;
  const int gb   = boff + lane;            // this lane's batch

  float v = 0.0f;
  float cv[64], cn[64];

  // preload tile 0
#pragma unroll
  for (int j = 0; j < 64; ++j) cv[j] = curT[j * B_DIM + gb];

  for (int k = 0; k < 32; ++k) {
    // issue next tile's loads first (drain under the 1024-cyc chain)
    if (k < 31) {
      const int tbase = (k + 1) * 64;
#pragma unroll
      for (int j = 0; j < 64; ++j) {
        const int tn = tbase + j;
        cn[j] = (tn < T_STEPS) ? curT[tn * B_DIM + gb] : 0.0f;
      }
    }

    const int t0  = k * 64;
    const int len = (T_STEPS - t0 < 64) ? (T_STEPS - t0) : 64;

    if (len == 64) {
#pragma unroll
      for (int j = 0; j < 64; ++j) {
        // exact R1 semantics: mul then add (no contraction), sub-reset
        v = __fadd_rn(__fmul_rn(BETA, v), cv[j]);
        const float d = v - VTH;
        const float s = (d >= 0.0f) ? 1.0f : 0.0f;
        v = (d >= 0.0f) ? d : v;
        sb[lane * 65 + j] = s;
      }
    } else {  // tail: len == 16
#pragma unroll
      for (int j = 0; j < 16; ++j) {
        v = __fadd_rn(__fmul_rn(BETA, v), cv[j]);
        const float d = v - VTH;
        const float s = (d >= 0.0f) ? 1.0f : 0.0f;
        v = (d >= 0.0f) ? d : v;
        sb[lane * 65 + j] = s;
      }
    }
    __syncthreads();

    // coalesced flush: row r = batch boff+r, 64 consecutive t per store
    if (t0 + lane < T_STEPS) {
#pragma unroll 8
      for (int r = 0; r < 64; ++r) {
        out[(size_t)(boff + r) * T_STEPS + t0 + lane] = sb[r * 65 + lane];
      }
    }
    __syncthreads();

    if (k < 31) {
#pragma unroll
      for (int j = 0; j < 64; ++j) cv[j] = cn[j];
    }
  }

  out[(size_t)B_DIM * T_STEPS + gb] = v;   // final Vmem
}

extern "C" void kernel_launch(void* const* d_in, const int* in_sizes, int n_in,
                              void* d_out, int out_size, void* d_ws, size_t ws_size,
                              hipStream_t stream) {
  const float* x    = (const float*)d_in[0];
  const float* W    = (const float*)d_in[1];
  const float* bias = (const float*)d_in[2];
  float* out  = (float*)d_out;
  float* curT = (float*)d_ws;              // 512000 floats = 2.05 MB scratch

  dense_rows<<<dim3(2048), dim3(256), 0, stream>>>(x, W, bias, curT);
  lif_scan<<<dim3(B_DIM / 64), dim3(64), 0, stream>>>(curT, out);
}